// Round 4
// baseline (372.123 us; speedup 1.0000x reference)
//
#include <hip/hip_runtime.h>
#include <cstdint>

typedef unsigned short u16;
typedef __attribute__((ext_vector_type(8))) short bf16x8;
typedef __attribute__((ext_vector_type(4))) float f32x4;

__device__ __forceinline__ u16 f2b(float x) {
  unsigned u = __float_as_uint(x);
  u += 0x7FFFu + ((u >> 16) & 1u);
  return (u16)(u >> 16);
}

__device__ __forceinline__ void gload16(const void* g, void* l) {
  __builtin_amdgcn_global_load_lds(
      (const __attribute__((address_space(1))) void*)g,
      (__attribute__((address_space(3))) void*)l, 16, 0, 0);
}

// row-dependent 16B-chunk swizzle (both-sides rule: inverse on global source,
// forward on LDS read — LDS dest of global_load_lds stays linear)
__device__ __forceinline__ int swz(int r) { return (r & 3) ^ ((r >> 2) & 3); }

template <int N>
__device__ __forceinline__ void vmwait() {
  if constexpr (N == 0) asm volatile("s_waitcnt vmcnt(0)" ::: "memory");
  else if constexpr (N == 3) asm volatile("s_waitcnt vmcnt(3)" ::: "memory");
  else if constexpr (N == 4) asm volatile("s_waitcnt vmcnt(4)" ::: "memory");
  else if constexpr (N == 6) asm volatile("s_waitcnt vmcnt(6)" ::: "memory");
  else if constexpr (N == 8) asm volatile("s_waitcnt vmcnt(8)" ::: "memory");
}

// stage one (operand, k-half) region: R rows x 32 bf16, L = R/128 loads/thread
template <int L>
__device__ __forceinline__ void stage_region(const u16* __restrict__ G,
                                             long long ld, int gcol,
                                             u16* L_, int tid) {
#pragma unroll
  for (int j = 0; j < L; ++j) {
    const int P = j * 512 + tid;
    const int r = P >> 2;
    const int cl = (P & 3) ^ swz(r);
    gload16(G + (long long)r * ld + gcol + cl * 8, L_ + P * 8);
  }
}

__device__ __forceinline__ bf16x8 frag(const u16* reg_, int row, int cA) {
  return *(const bf16x8*)(reg_ + row * 32 + ((cA ^ swz(row)) << 3));
}

// ---------------------------------------------------------------------------
// 8-phase MFMA GEMM (m201-style schedule in plain HIP).
// C = A @ B^T; A [M,K] row-major, B [N,K] row-major. BK=64, 512 thr, 8 waves.
// Tile = BM x BN, BM = WM*MR*16, BN = WN*NR*16. 2 LDS buffers, each with 4
// regions {A-k0, A-k1, B-k0, B-k1}; 1 region staged per phase; vmcnt counted
// at phases j1/j3 only (never drained mid-loop).
// EPI: 0=QKV split  1=theta->cat halves  2=bf16  3=f32+bias  4=f32 plain
// ---------------------------------------------------------------------------
template <int EPI, int WM, int WN, int MR, int NR>
__global__ __launch_bounds__(512, 2) void g8p(
    const u16* __restrict__ A, long long lda, long long sAz,
    const u16* __restrict__ B, long long ldb, long long sBz,
    void* __restrict__ C0, void* __restrict__ C1, void* __restrict__ C2,
    long long ldc, long long sCz, int K,
    const float* __restrict__ b0, const float* __restrict__ b1,
    const float* __restrict__ b2, float preScale, const float* __restrict__ esp) {
  constexpr int BM = WM * MR * 16, BN = WN * NR * 16;
  constexpr int LA = BM / 128, LB = BN / 128;   // loads/thread per region
  constexpr int AHALF = BM * 32;                // u16 per A k-half region
  constexpr int BHALF = BN * 32;
  constexpr int BUFU = 2 * (AHALF + BHALF);     // u16 per K-tile buffer
  constexpr int NH = NR / 2;
  __shared__ __align__(16) u16 lds[2 * BUFU];

  // XCD-aware bijective swizzle within the z-slice (S % 8 == 0 for all grids)
  const int gx = gridDim.x, S = gx * gridDim.y;
  const int hw = blockIdx.y * gx + blockIdx.x;
  const int l = (hw & 7) * (S >> 3) + (hw >> 3);
  const int bx = l % gx, by = l / gx;
  const int z = blockIdx.z;
  const long long tM = (long long)by * BM;
  const long long tN = (long long)bx * BN;
  const u16* Ab = A + z * sAz + tM * lda;
  const u16* Bb = B + z * sBz + tN * ldb;
  const int tid = threadIdx.x;
  const int NT = K >> 6;

  // prologue: tile0 fully + tile1 k0 (issue order = completion-count order)
  stage_region<LA>(Ab, lda, 0,  lds, tid);                         // A-k0(0)
  stage_region<LB>(Bb, ldb, 0,  lds + 2 * AHALF, tid);             // B-k0(0)
  stage_region<LA>(Ab, lda, 32, lds + AHALF, tid);                 // A-k1(0)
  stage_region<LB>(Bb, ldb, 32, lds + 2 * AHALF + BHALF, tid);     // B-k1(0)
  stage_region<LA>(Ab, lda, 64, lds + BUFU, tid);                  // A-k0(1)
  stage_region<LB>(Bb, ldb, 64, lds + BUFU + 2 * AHALF, tid);      // B-k0(1)
  vmwait<2 * (LA + LB)>();   // A-k0(0), B-k0(0) landed
  __builtin_amdgcn_s_barrier();

  const int wid = tid >> 6, lane = tid & 63;
  const int wm = wid / WN, wn = wid % WN;
  const int wr = wm * MR * 16, wc = wn * NR * 16;
  const int lr = lane & 15, cA = lane >> 4;
  f32x4 acc[MR][NR] = {};

  for (int t = 0; t < NT; ++t) {
    u16* bufc = lds + (t & 1) * BUFU;
    u16* bufn = lds + ((t + 1) & 1) * BUFU;
    const u16* Ak0p = bufc;
    const u16* Ak1p = bufc + AHALF;
    const u16* Bk0p = bufc + 2 * AHALF;
    const u16* Bk1p = bufc + 2 * AHALF + BHALF;
    bf16x8 a[MR], b[NH];

    // -------- phase 0: k0 x n-lo; stage A-k1(t+1)
#pragma unroll
    for (int m = 0; m < MR; ++m) a[m] = frag(Ak0p, wr + m * 16 + lr, cA);
#pragma unroll
    for (int n = 0; n < NH; ++n) b[n] = frag(Bk0p, wc + n * 16 + lr, cA);
    if (t + 1 < NT)
      stage_region<LA>(Ab, lda, (t + 1) * 64 + 32, bufn + AHALF, tid);
    __builtin_amdgcn_s_barrier();
    asm volatile("s_waitcnt lgkmcnt(0)" ::: "memory");
    __builtin_amdgcn_s_setprio(1);
#pragma unroll
    for (int m = 0; m < MR; ++m)
#pragma unroll
      for (int n = 0; n < NH; ++n)
        acc[m][n] = __builtin_amdgcn_mfma_f32_16x16x32_bf16(a[m], b[n],
                                                            acc[m][n], 0, 0, 0);
    __builtin_amdgcn_s_setprio(0);
    __builtin_amdgcn_s_barrier();

    // -------- phase 1: k0 x n-hi; stage B-k1(t+1); vmcnt for k1(t)
#pragma unroll
    for (int n = 0; n < NH; ++n) b[n] = frag(Bk0p, wc + (NH + n) * 16 + lr, cA);
    if (t + 1 < NT)
      stage_region<LB>(Bb, ldb, (t + 1) * 64 + 32, bufn + 2 * AHALF + BHALF, tid);
    if (t < NT - 1) vmwait<2 * (LA + LB)>(); else vmwait<0>();
    __builtin_amdgcn_s_barrier();
    asm volatile("s_waitcnt lgkmcnt(0)" ::: "memory");
    __builtin_amdgcn_s_setprio(1);
#pragma unroll
    for (int m = 0; m < MR; ++m)
#pragma unroll
      for (int n = 0; n < NH; ++n)
        acc[m][NH + n] = __builtin_amdgcn_mfma_f32_16x16x32_bf16(
            a[m], b[n], acc[m][NH + n], 0, 0, 0);
    __builtin_amdgcn_s_setprio(0);
    __builtin_amdgcn_s_barrier();

    // -------- phase 2: k1 x n-lo; stage A-k0(t+2)
#pragma unroll
    for (int m = 0; m < MR; ++m) a[m] = frag(Ak1p, wr + m * 16 + lr, cA);
#pragma unroll
    for (int n = 0; n < NH; ++n) b[n] = frag(Bk1p, wc + n * 16 + lr, cA);
    if (t + 2 < NT)
      stage_region<LA>(Ab, lda, (t + 2) * 64, bufc, tid);
    __builtin_amdgcn_s_barrier();
    asm volatile("s_waitcnt lgkmcnt(0)" ::: "memory");
    __builtin_amdgcn_s_setprio(1);
#pragma unroll
    for (int m = 0; m < MR; ++m)
#pragma unroll
      for (int n = 0; n < NH; ++n)
        acc[m][n] = __builtin_amdgcn_mfma_f32_16x16x32_bf16(a[m], b[n],
                                                            acc[m][n], 0, 0, 0);
    __builtin_amdgcn_s_setprio(0);
    __builtin_amdgcn_s_barrier();

    // -------- phase 3: k1 x n-hi; stage B-k0(t+2); vmcnt for k0(t+1)
#pragma unroll
    for (int n = 0; n < NH; ++n) b[n] = frag(Bk1p, wc + (NH + n) * 16 + lr, cA);
    if (t + 2 < NT)
      stage_region<LB>(Bb, ldb, (t + 2) * 64, bufc + 2 * AHALF, tid);
    if (t < NT - 2) vmwait<2 * (LA + LB)>();
    else if (t == NT - 2) vmwait<LA + LB>();
    __builtin_amdgcn_s_barrier();
    asm volatile("s_waitcnt lgkmcnt(0)" ::: "memory");
    __builtin_amdgcn_s_setprio(1);
#pragma unroll
    for (int m = 0; m < MR; ++m)
#pragma unroll
      for (int n = 0; n < NH; ++n)
        acc[m][NH + n] = __builtin_amdgcn_mfma_f32_16x16x32_bf16(
            a[m], b[n], acc[m][NH + n], 0, 0, 0);
    __builtin_amdgcn_s_setprio(0);
    __builtin_amdgcn_s_barrier();
  }

  // epilogue: C/D map col=lane&15, row=(lane>>4)*4+reg
  const int rr = (lane >> 4) << 2;
  float ps = preScale, mul = 1.0f;
  if constexpr (EPI == 1) {
    ps = (z == 0) ? preScale : 1.0f;
    mul = (z == 0) ? esp[0] : 1.0f;
  }
#pragma unroll
  for (int m = 0; m < MR; ++m) {
#pragma unroll
    for (int n = 0; n < NR; ++n) {
      const int col = (int)tN + wc + n * 16 + lr;
#pragma unroll
      for (int r = 0; r < 4; ++r) {
        const long long row = tM + wr + m * 16 + rr + r;
        const float v = acc[m][n][r];
        if constexpr (EPI == 0) {
          const int g = col >> 10, cc = col & 1023;
          if (g == 0)      ((u16*)C0)[row * 2048 + cc] = f2b((v + b0[cc]) * 0.03125f);
          else if (g == 1) ((u16*)C1)[row * 2048 + cc] = f2b(v + b1[cc]);
          else             ((u16*)C2)[row * 1024 + cc] = f2b(v + b2[cc]);
        } else if constexpr (EPI == 1) {
          const float tt = v * ps + b0[col];
          const float sg = 1.f / (1.f + __expf(-tt));
          ((u16*)C0)[z * sCz + row * ldc + col] = f2b(mul * cospif(sg));
        } else if constexpr (EPI == 2) {
          ((u16*)C0)[z * sCz + row * ldc + col] = f2b(v);
        } else if constexpr (EPI == 3) {
          ((float*)C0)[z * sCz + row * ldc + col] = v + b0[col];
        } else {
          ((float*)C0)[z * sCz + row * ldc + col] = v;
        }
      }
    }
  }
}

// row softmax over [8192][2048]: fp32 in-place + bf16 copy
__global__ __launch_bounds__(256) void softmax_rows(float* __restrict__ L,
                                                    u16* __restrict__ AB) {
  const long long row = blockIdx.x;
  float4* p4 = (float4*)(L + row * 2048);
  const int tid = threadIdx.x;
  float4 a = p4[tid], b = p4[tid + 256];
  float m = fmaxf(fmaxf(fmaxf(a.x, a.y), fmaxf(a.z, a.w)),
                  fmaxf(fmaxf(b.x, b.y), fmaxf(b.z, b.w)));
#pragma unroll
  for (int o = 32; o > 0; o >>= 1) m = fmaxf(m, __shfl_xor(m, o));
  __shared__ float rmax[4], rsum[4];
  const int wid = tid >> 6, lane = tid & 63;
  if (lane == 0) rmax[wid] = m;
  __syncthreads();
  m = fmaxf(fmaxf(rmax[0], rmax[1]), fmaxf(rmax[2], rmax[3]));
  a.x = __expf(a.x - m); a.y = __expf(a.y - m);
  a.z = __expf(a.z - m); a.w = __expf(a.w - m);
  b.x = __expf(b.x - m); b.y = __expf(b.y - m);
  b.z = __expf(b.z - m); b.w = __expf(b.w - m);
  float s = a.x + a.y + a.z + a.w + b.x + b.y + b.z + b.w;
#pragma unroll
  for (int o = 32; o > 0; o >>= 1) s += __shfl_xor(s, o);
  if (lane == 0) rsum[wid] = s;
  __syncthreads();
  s = rsum[0] + rsum[1] + rsum[2] + rsum[3];
  const float inv = 1.0f / s;
  a.x *= inv; a.y *= inv; a.z *= inv; a.w *= inv;
  b.x *= inv; b.y *= inv; b.z *= inv; b.w *= inv;
  p4[tid] = a;
  p4[tid + 256] = b;
  ushort4* o4 = (ushort4*)(AB + row * 2048);
  o4[tid]       = make_ushort4(f2b(a.x), f2b(a.y), f2b(a.z), f2b(a.w));
  o4[tid + 256] = make_ushort4(f2b(b.x), f2b(b.y), f2b(b.z), f2b(b.w));
}

__global__ __launch_bounds__(256) void cvt_x(const float* __restrict__ X,
                                             u16* __restrict__ XB) {
  const int i = blockIdx.x * 256 + threadIdx.x;
  float4 v = ((const float4*)X)[i];
  ((ushort4*)XB)[i] = make_ushort4(f2b(v.x), f2b(v.y), f2b(v.z), f2b(v.w));
}

// transpose+convert 5 weight matrices [1024,1024] f32 -> bf16 W^T
__global__ void cvt_w(const float* __restrict__ W0, const float* __restrict__ W1,
                      const float* __restrict__ W2, const float* __restrict__ W3,
                      const float* __restrict__ W4, u16* __restrict__ WT) {
  __shared__ float t[32][33];
  const int z = blockIdx.z;
  const float* W = (z == 0) ? W0 : (z == 1) ? W1 : (z == 2) ? W2 : (z == 3) ? W3 : W4;
  u16* D = WT + (long long)z * 1024 * 1024;
  const int c0 = blockIdx.x * 32, r0 = blockIdx.y * 32;
  const int tx = threadIdx.x, ty = threadIdx.y;
#pragma unroll
  for (int i = 0; i < 4; ++i)
    t[ty + i * 8][tx] = W[(long long)(r0 + ty + i * 8) * 1024 + c0 + tx];
  __syncthreads();
#pragma unroll
  for (int i = 0; i < 4; ++i)
    D[(long long)(c0 + ty + i * 8) * 1024 + r0 + tx] = f2b(t[tx][ty + i * 8]);
}

// Vb [8192,1024] bf16 -> VT [4][1024,2048] bf16
__global__ void transpose_v(const u16* __restrict__ Vb, u16* __restrict__ VT) {
  __shared__ u16 t[32][33];
  const int b = blockIdx.z;
  const u16* V = Vb + (long long)b * 2048 * 1024;
  u16* O = VT + (long long)b * 1024 * 2048;
  const int d0 = blockIdx.x * 32, s0 = blockIdx.y * 32;
  const int tx = threadIdx.x, ty = threadIdx.y;
#pragma unroll
  for (int i = 0; i < 4; ++i)
    t[ty + i * 8][tx] = V[(long long)(s0 + ty + i * 8) * 1024 + d0 + tx];
  __syncthreads();
#pragma unroll
  for (int i = 0; i < 4; ++i)
    O[(long long)(d0 + ty + i * 8) * 2048 + s0 + tx] = t[tx][ty + i * 8];
}

extern "C" void kernel_launch(void* const* d_in, const int* in_sizes, int n_in,
                              void* d_out, int out_size, void* d_ws,
                              size_t ws_size, hipStream_t stream) {
  const float* x  = (const float*)d_in[0];
  const float* Wq = (const float*)d_in[1];
  const float* bq = (const float*)d_in[2];
  const float* Wk = (const float*)d_in[3];
  const float* bk = (const float*)d_in[4];
  const float* Wv = (const float*)d_in[5];
  const float* bv = (const float*)d_in[6];
  const float* Wt = (const float*)d_in[7];
  const float* bt = (const float*)d_in[8];
  const float* Wo = (const float*)d_in[9];
  const float* bo = (const float*)d_in[10];
  const float* es = (const float*)d_in[11];

  char* ws = (char*)d_ws;
  u16* WT   = (u16*)(ws);               // 5x [1024,1024] bf16 (WqT,WkT,WvT,WtT,WoT)
  u16* XB   = (u16*)(ws + 10485760);    // [8192,1024] bf16; later AV
  u16* Qcat = (u16*)(ws + 27262976);    // [8192,2048] bf16: Q/32 | es*r_q ; later ATT
  u16* Kcat = Qcat + 16777216;          // [8192,2048] bf16: K | r_k
  u16* Vb   = (u16*)(ws + 94371840);    // [8192,1024] bf16
  u16* VT   = (u16*)(ws + 111149056);   // [4][1024,2048] bf16
  u16* WtT  = WT + 3 * 1048576;
  u16* WoT  = WT + 4 * 1048576;
  u16* ATT  = Qcat;
  u16* AV   = XB;

  float* outO = (float*)d_out;          // [4,2048,1024]
  float* outA = outO + 8388608;         // [4,2048,2048]

  cvt_x<<<8192, 256, 0, stream>>>(x, XB);
  cvt_w<<<dim3(32, 32, 5), dim3(32, 8), 0, stream>>>(Wq, Wk, Wv, Wt, Wo, WT);
  // QKV projection (128x256 tiles, grid 768 = 3x256 CUs, balanced)
  g8p<0, 4, 2, 2, 8><<<dim3(12, 64, 1), 512, 0, stream>>>(
      XB, 1024, 0, WT, 1024, 0, Qcat, Kcat, Vb, 0, 0, 1024, bq, bk, bv, 1.f, nullptr);
  // theta (z=0: Q/32 -> es*r_q, ps=32; z=1: K -> r_k, ps=1), grid 2x256
  g8p<1, 4, 2, 2, 8><<<dim3(4, 64, 2), 512, 0, stream>>>(
      Qcat, 2048, 16777216LL, WtT, 1024, 0, Qcat + 1024, nullptr, nullptr,
      2048, 16777216LL, 1024, bt, nullptr, nullptr, 32.f, es);
  transpose_v<<<dim3(32, 64, 4), dim3(32, 8), 0, stream>>>(Vb, VT);
  // logits = Qcat @ Kcat^T (K=2048), 256x256 tiles, grid 256
  g8p<4, 2, 4, 8, 4><<<dim3(8, 8, 4), 512, 0, stream>>>(
      Qcat, 2048, 4194304LL, Kcat, 2048, 4194304LL, outA, nullptr, nullptr,
      2048, 4194304LL, 2048, nullptr, nullptr, nullptr, 1.f, nullptr);
  softmax_rows<<<8192, 256, 0, stream>>>(outA, ATT);
  // attn @ V (128x256 tiles, grid 256)
  g8p<2, 4, 2, 2, 8><<<dim3(4, 16, 4), 512, 0, stream>>>(
      ATT, 2048, 4194304LL, VT, 2048, 2097152LL, AV, nullptr, nullptr,
      1024, 2097152LL, 2048, nullptr, nullptr, nullptr, 1.f, nullptr);
  // output projection (grid 256)
  g8p<3, 4, 2, 2, 8><<<dim3(4, 64, 1), 512, 0, stream>>>(
      AV, 1024, 0, WoT, 1024, 0, outO, nullptr, nullptr,
      1024, 0, 1024, bo, nullptr, nullptr, 1.f, nullptr);
}

// Round 5
// 343.102 us; speedup vs baseline: 1.0846x; 1.0846x over previous
//
#include <hip/hip_runtime.h>
#include <cstdint>

typedef unsigned short u16;
typedef __attribute__((ext_vector_type(8))) short bf16x8;
typedef __attribute__((ext_vector_type(4))) float f32x4;

__device__ __forceinline__ u16 f2b(float x) {
  unsigned u = __float_as_uint(x);
  u += 0x7FFFu + ((u >> 16) & 1u);
  return (u16)(u >> 16);
}

__device__ __forceinline__ void gload16(const void* g, void* l) {
  __builtin_amdgcn_global_load_lds(
      (const __attribute__((address_space(1))) void*)g,
      (__attribute__((address_space(3))) void*)l, 16, 0, 0);
}

template <int N>
__device__ __forceinline__ void vmwait() {
  if constexpr (N == 0) asm volatile("s_waitcnt vmcnt(0)" ::: "memory");
  else if constexpr (N == 3) asm volatile("s_waitcnt vmcnt(3)" ::: "memory");
  else if constexpr (N == 4) asm volatile("s_waitcnt vmcnt(4)" ::: "memory");
  else if constexpr (N == 6) asm volatile("s_waitcnt vmcnt(6)" ::: "memory");
  else if constexpr (N == 8) asm volatile("s_waitcnt vmcnt(8)" ::: "memory");
}

// Region rows are 64 bf16 = 128 B = 8 chunks of 16 B. Linear layout is a
// 16-way bank conflict on column reads; XOR chunk with row&7 -> 2-way.
// Both-sides rule (m231): LDS dest linear, global source inverse-swizzled,
// read swizzled.
template <int L>
__device__ __forceinline__ void stage_half(const u16* __restrict__ G,
                                           long long ld, int kb,
                                           u16* Ldst, int tid) {
#pragma unroll
  for (int j = 0; j < L; ++j) {
    const int P = j * 512 + tid;
    const int r = P >> 3, c = P & 7;
    gload16(G + (long long)r * ld + kb + ((c ^ (r & 7)) << 3), Ldst + P * 8);
  }
}

__device__ __forceinline__ bf16x8 fr8(const u16* R, int row, int chunk) {
  return *(const bf16x8*)(R + row * 64 + ((chunk ^ (row & 7)) << 3));
}

// ---------------------------------------------------------------------------
// Faithful m201-style quadrant-scheduled GEMM. C = A @ B^T, BK=64, 512 thr,
// 8 waves (2M x 4N). Tile BM x 256, BM = 64*FM. Halves = M/N-halves at full
// BK. Per tile 4 phases = C-quadrants (Alo,Blo)(Alo,Bhi)(Ahi,Blo)(Ahi,Bhi);
// 1 half staged per phase; counted vmcnt at p0/p3 BEFORE the barrier that
// precedes the dependent reads; A-frags reused across n-quadrants.
// Stage->use distance 4-6 phases; max in flight 4-5 halves.
// ---------------------------------------------------------------------------
template <int FM, int MODE>  // MODE: 0 steady, 1 t=NT-2, 2 t=NT-1
__device__ __forceinline__ void tile_body(
    u16* cur, u16* oth, const u16* GA_lo, const u16* GA_hi,
    const u16* GB_lo, const u16* GB_hi, long long lda, long long ldb,
    int kb1, int kb2, int wm, int wn, int lr, int cA, int tid,
    f32x4 (&acc)[2][2][FM][2]) {
  constexpr int LA = FM / 2, LB = 2;
  constexpr int AH = 2048 * FM, BH = 8192;
  const u16* Alo = cur;
  const u16* Ahi = cur + AH;
  const u16* Blo = cur + 2 * AH;
  const u16* Bhi = cur + 2 * AH + BH;
  const int ar = wm * (FM * 16) + lr;
  const int br = wn * 32 + lr;
  bf16x8 a[FM][2], b[2][2];

  // ---- p0: read aL + bL; stage Ahi(t+1)->oth; vmcnt ensures Bhi(t),Ahi(t)
#pragma unroll
  for (int f = 0; f < FM; ++f) {
    a[f][0] = fr8(Alo, ar + f * 16, cA);
    a[f][1] = fr8(Alo, ar + f * 16, 4 + cA);
  }
#pragma unroll
  for (int g = 0; g < 2; ++g) {
    b[g][0] = fr8(Blo, br + g * 16, cA);
    b[g][1] = fr8(Blo, br + g * 16, 4 + cA);
  }
  if constexpr (MODE < 2) stage_half<LA>(GA_hi, lda, kb1, oth + AH, tid);
  if constexpr (FM == 4) asm volatile("s_waitcnt lgkmcnt(8)" ::: "memory");
  if constexpr (MODE < 2) vmwait<2 * LA + 2>(); else vmwait<0>();
  __builtin_amdgcn_s_barrier();
  asm volatile("s_waitcnt lgkmcnt(0)" ::: "memory");
  __builtin_amdgcn_s_setprio(1);
#pragma unroll
  for (int kh = 0; kh < 2; ++kh)
#pragma unroll
    for (int f = 0; f < FM; ++f)
#pragma unroll
      for (int g = 0; g < 2; ++g)
        acc[0][0][f][g] = __builtin_amdgcn_mfma_f32_16x16x32_bf16(
            a[f][kh], b[g][kh], acc[0][0][f][g], 0, 0, 0);
  __builtin_amdgcn_s_setprio(0);
  __builtin_amdgcn_s_barrier();

  // ---- p1: read bH (reuse a); stage Bhi(t+1)->oth
#pragma unroll
  for (int g = 0; g < 2; ++g) {
    b[g][0] = fr8(Bhi, br + g * 16, cA);
    b[g][1] = fr8(Bhi, br + g * 16, 4 + cA);
  }
  if constexpr (MODE < 2) stage_half<LB>(GB_hi, ldb, kb1, oth + 2 * AH + BH, tid);
  __builtin_amdgcn_s_barrier();
  asm volatile("s_waitcnt lgkmcnt(0)" ::: "memory");
  __builtin_amdgcn_s_setprio(1);
#pragma unroll
  for (int kh = 0; kh < 2; ++kh)
#pragma unroll
    for (int f = 0; f < FM; ++f)
#pragma unroll
      for (int g = 0; g < 2; ++g)
        acc[0][1][f][g] = __builtin_amdgcn_mfma_f32_16x16x32_bf16(
            a[f][kh], b[g][kh], acc[0][1][f][g], 0, 0, 0);
  __builtin_amdgcn_s_setprio(0);
  __builtin_amdgcn_s_barrier();

  // ---- p2: read aH + bL; stage Alo(t+2)->cur (Alo reads done since p0)
#pragma unroll
  for (int f = 0; f < FM; ++f) {
    a[f][0] = fr8(Ahi, ar + f * 16, cA);
    a[f][1] = fr8(Ahi, ar + f * 16, 4 + cA);
  }
#pragma unroll
  for (int g = 0; g < 2; ++g) {
    b[g][0] = fr8(Blo, br + g * 16, cA);
    b[g][1] = fr8(Blo, br + g * 16, 4 + cA);
  }
  if constexpr (MODE == 0) stage_half<LA>(GA_lo, lda, kb2, cur, tid);
  if constexpr (FM == 4) asm volatile("s_waitcnt lgkmcnt(8)" ::: "memory");
  __builtin_amdgcn_s_barrier();
  asm volatile("s_waitcnt lgkmcnt(0)" ::: "memory");
  __builtin_amdgcn_s_setprio(1);
#pragma unroll
  for (int kh = 0; kh < 2; ++kh)
#pragma unroll
    for (int f = 0; f < FM; ++f)
#pragma unroll
      for (int g = 0; g < 2; ++g)
        acc[1][0][f][g] = __builtin_amdgcn_mfma_f32_16x16x32_bf16(
            a[f][kh], b[g][kh], acc[1][0][f][g], 0, 0, 0);
  __builtin_amdgcn_s_setprio(0);
  __builtin_amdgcn_s_barrier();

  // ---- p3: read bH; stage Blo(t+2)->cur; vmcnt ensures Alo(t+1),Blo(t+1)
#pragma unroll
  for (int g = 0; g < 2; ++g) {
    b[g][0] = fr8(Bhi, br + g * 16, cA);
    b[g][1] = fr8(Bhi, br + g * 16, 4 + cA);
  }
  if constexpr (MODE == 0) stage_half<LB>(GB_lo, ldb, kb2, cur + 2 * AH, tid);
  if constexpr (MODE == 0) vmwait<2 * LA + 4>();
  else if constexpr (MODE == 1) vmwait<LA + 2>();
  __builtin_amdgcn_s_barrier();
  asm volatile("s_waitcnt lgkmcnt(0)" ::: "memory");
  __builtin_amdgcn_s_setprio(1);
#pragma unroll
  for (int kh = 0; kh < 2; ++kh)
#pragma unroll
    for (int f = 0; f < FM; ++f)
#pragma unroll
      for (int g = 0; g < 2; ++g)
        acc[1][1][f][g] = __builtin_amdgcn_mfma_f32_16x16x32_bf16(
            a[f][kh], b[g][kh], acc[1][1][f][g], 0, 0, 0);
  __builtin_amdgcn_s_setprio(0);
  __builtin_amdgcn_s_barrier();
}

// EPI: 0=QKV split  1=theta->cat halves  2=bf16  3=f32+bias  4=f32 plain
template <int EPI, int FM>
__global__ __launch_bounds__(512, 2) void g8q(
    const u16* __restrict__ A, long long lda, long long sAz,
    const u16* __restrict__ B, long long ldb, long long sBz,
    void* __restrict__ C0, void* __restrict__ C1, void* __restrict__ C2,
    long long ldc, long long sCz, int K,
    const float* __restrict__ b0, const float* __restrict__ b1,
    const float* __restrict__ b2, float preScale, const float* __restrict__ esp) {
  constexpr int BM = 64 * FM;
  constexpr int LA = FM / 2, LB = 2;
  constexpr int AH = 2048 * FM, BH = 8192;
  constexpr int BUFU = 2 * AH + 2 * BH;
  __shared__ __align__(16) u16 lds[2 * BUFU];
  u16* buf0 = lds;
  u16* buf1 = lds + BUFU;

  // XCD-aware bijective swizzle within the z-slice (S % 8 == 0 everywhere)
  const int gx = gridDim.x, S = gx * gridDim.y;
  const int hw = blockIdx.y * gx + blockIdx.x;
  const int l = (hw & 7) * (S >> 3) + (hw >> 3);
  const int bx = l % gx, by = l / gx;
  const int z = blockIdx.z;
  const long long tM = (long long)by * BM;
  const long long tN = (long long)bx * 256;
  const u16* Ab = A + z * sAz + tM * lda;
  const u16* Bb = B + z * sBz + tN * ldb;
  const u16* GA_lo = Ab;
  const u16* GA_hi = Ab + (long long)(BM / 2) * lda;
  const u16* GB_lo = Bb;
  const u16* GB_hi = Bb + 128 * ldb;
  const int tid = threadIdx.x;
  const int NT = K >> 6;  // NT even, >= 4

  // prologue: Alo0, Blo0, Ahi0, Bhi0, Alo1, Blo1; then wait + barrier
  stage_half<LA>(GA_lo, lda, 0, buf0, tid);
  stage_half<LB>(GB_lo, ldb, 0, buf0 + 2 * AH, tid);
  stage_half<LA>(GA_hi, lda, 0, buf0 + AH, tid);
  stage_half<LB>(GB_hi, ldb, 0, buf0 + 2 * AH + BH, tid);
  stage_half<LA>(GA_lo, lda, 64, buf1, tid);
  stage_half<LB>(GB_lo, ldb, 64, buf1 + 2 * AH, tid);
  vmwait<2 * LA + 4>();
  __builtin_amdgcn_s_barrier();

  const int wid = tid >> 6, lane = tid & 63;
  const int wm = wid >> 2, wn = wid & 3;
  const int lr = lane & 15, cA = lane >> 4;
  f32x4 acc[2][2][FM][2] = {};

  for (int t = 0; t + 2 < NT; t += 2) {
    tile_body<FM, 0>(buf0, buf1, GA_lo, GA_hi, GB_lo, GB_hi, lda, ldb,
                     (t + 1) * 64, (t + 2) * 64, wm, wn, lr, cA, tid, acc);
    tile_body<FM, 0>(buf1, buf0, GA_lo, GA_hi, GB_lo, GB_hi, lda, ldb,
                     (t + 2) * 64, (t + 3) * 64, wm, wn, lr, cA, tid, acc);
  }
  tile_body<FM, 1>(buf0, buf1, GA_lo, GA_hi, GB_lo, GB_hi, lda, ldb,
                   (NT - 1) * 64, 0, wm, wn, lr, cA, tid, acc);
  tile_body<FM, 2>(buf1, buf0, GA_lo, GA_hi, GB_lo, GB_hi, lda, ldb,
                   0, 0, wm, wn, lr, cA, tid, acc);

  // epilogue: C/D map col=lane&15, row=(lane>>4)*4+reg
  const int rr = (lane >> 4) << 2;
  float ps = preScale, mul = 1.0f;
  if constexpr (EPI == 1) {
    ps = (z == 0) ? preScale : 1.0f;
    mul = (z == 0) ? esp[0] : 1.0f;
  }
#pragma unroll
  for (int mh = 0; mh < 2; ++mh) {
#pragma unroll
    for (int nh = 0; nh < 2; ++nh) {
#pragma unroll
      for (int f = 0; f < FM; ++f) {
#pragma unroll
        for (int g = 0; g < 2; ++g) {
          const int col = (int)tN + nh * 128 + wn * 32 + g * 16 + lr;
          const f32x4 vv = acc[mh][nh][f][g];
#pragma unroll
          for (int r = 0; r < 4; ++r) {
            const long long row =
                tM + mh * (BM / 2) + wm * (FM * 16) + f * 16 + rr + r;
            const float v = vv[r];
            if constexpr (EPI == 0) {
              const int gg = col >> 10, cc = col & 1023;
              if (gg == 0)      ((u16*)C0)[row * 2048 + cc] = f2b((v + b0[cc]) * 0.03125f);
              else if (gg == 1) ((u16*)C1)[row * 2048 + cc] = f2b(v + b1[cc]);
              else              ((u16*)C2)[row * 1024 + cc] = f2b(v + b2[cc]);
            } else if constexpr (EPI == 1) {
              const float tt = v * ps + b0[col];
              const float sg = 1.f / (1.f + __expf(-tt));
              ((u16*)C0)[z * sCz + row * ldc + col] = f2b(mul * cospif(sg));
            } else if constexpr (EPI == 2) {
              ((u16*)C0)[z * sCz + row * ldc + col] = f2b(v);
            } else if constexpr (EPI == 3) {
              ((float*)C0)[z * sCz + row * ldc + col] = v + b0[col];
            } else {
              ((float*)C0)[z * sCz + row * ldc + col] = v;
            }
          }
        }
      }
    }
  }
}

// row softmax over [8192][2048]: fp32 in-place + bf16 copy
__global__ __launch_bounds__(256) void softmax_rows(float* __restrict__ L,
                                                    u16* __restrict__ AB) {
  const long long row = blockIdx.x;
  float4* p4 = (float4*)(L + row * 2048);
  const int tid = threadIdx.x;
  float4 a = p4[tid], b = p4[tid + 256];
  float m = fmaxf(fmaxf(fmaxf(a.x, a.y), fmaxf(a.z, a.w)),
                  fmaxf(fmaxf(b.x, b.y), fmaxf(b.z, b.w)));
#pragma unroll
  for (int o = 32; o > 0; o >>= 1) m = fmaxf(m, __shfl_xor(m, o));
  __shared__ float rmax[4], rsum[4];
  const int wid = tid >> 6, lane = tid & 63;
  if (lane == 0) rmax[wid] = m;
  __syncthreads();
  m = fmaxf(fmaxf(rmax[0], rmax[1]), fmaxf(rmax[2], rmax[3]));
  a.x = __expf(a.x - m); a.y = __expf(a.y - m);
  a.z = __expf(a.z - m); a.w = __expf(a.w - m);
  b.x = __expf(b.x - m); b.y = __expf(b.y - m);
  b.z = __expf(b.z - m); b.w = __expf(b.w - m);
  float s = a.x + a.y + a.z + a.w + b.x + b.y + b.z + b.w;
#pragma unroll
  for (int o = 32; o > 0; o >>= 1) s += __shfl_xor(s, o);
  if (lane == 0) rsum[wid] = s;
  __syncthreads();
  s = rsum[0] + rsum[1] + rsum[2] + rsum[3];
  const float inv = 1.0f / s;
  a.x *= inv; a.y *= inv; a.z *= inv; a.w *= inv;
  b.x *= inv; b.y *= inv; b.z *= inv; b.w *= inv;
  p4[tid] = a;
  p4[tid + 256] = b;
  ushort4* o4 = (ushort4*)(AB + row * 2048);
  o4[tid]       = make_ushort4(f2b(a.x), f2b(a.y), f2b(a.z), f2b(a.w));
  o4[tid + 256] = make_ushort4(f2b(b.x), f2b(b.y), f2b(b.z), f2b(b.w));
}

__global__ __launch_bounds__(256) void cvt_x(const float* __restrict__ X,
                                             u16* __restrict__ XB) {
  const int i = blockIdx.x * 256 + threadIdx.x;
  float4 v = ((const float4*)X)[i];
  ((ushort4*)XB)[i] = make_ushort4(f2b(v.x), f2b(v.y), f2b(v.z), f2b(v.w));
}

// transpose+convert 5 weight matrices [1024,1024] f32 -> bf16 W^T
__global__ void cvt_w(const float* __restrict__ W0, const float* __restrict__ W1,
                      const float* __restrict__ W2, const float* __restrict__ W3,
                      const float* __restrict__ W4, u16* __restrict__ WT) {
  __shared__ float t[32][33];
  const int z = blockIdx.z;
  const float* W = (z == 0) ? W0 : (z == 1) ? W1 : (z == 2) ? W2 : (z == 3) ? W3 : W4;
  u16* D = WT + (long long)z * 1024 * 1024;
  const int c0 = blockIdx.x * 32, r0 = blockIdx.y * 32;
  const int tx = threadIdx.x, ty = threadIdx.y;
#pragma unroll
  for (int i = 0; i < 4; ++i)
    t[ty + i * 8][tx] = W[(long long)(r0 + ty + i * 8) * 1024 + c0 + tx];
  __syncthreads();
#pragma unroll
  for (int i = 0; i < 4; ++i)
    D[(long long)(c0 + ty + i * 8) * 1024 + r0 + tx] = f2b(t[tx][ty + i * 8]);
}

// Vb [8192,1024] bf16 -> VT [4][1024,2048] bf16
__global__ void transpose_v(const u16* __restrict__ Vb, u16* __restrict__ VT) {
  __shared__ u16 t[32][33];
  const int b = blockIdx.z;
  const u16* V = Vb + (long long)b * 2048 * 1024;
  u16* O = VT + (long long)b * 1024 * 2048;
  const int d0 = blockIdx.x * 32, s0 = blockIdx.y * 32;
  const int tx = threadIdx.x, ty = threadIdx.y;
#pragma unroll
  for (int i = 0; i < 4; ++i)
    t[ty + i * 8][tx] = V[(long long)(s0 + ty + i * 8) * 1024 + d0 + tx];
  __syncthreads();
#pragma unroll
  for (int i = 0; i < 4; ++i)
    O[(long long)(d0 + ty + i * 8) * 2048 + s0 + tx] = t[tx][ty + i * 8];
}

extern "C" void kernel_launch(void* const* d_in, const int* in_sizes, int n_in,
                              void* d_out, int out_size, void* d_ws,
                              size_t ws_size, hipStream_t stream) {
  const float* x  = (const float*)d_in[0];
  const float* Wq = (const float*)d_in[1];
  const float* bq = (const float*)d_in[2];
  const float* Wk = (const float*)d_in[3];
  const float* bk = (const float*)d_in[4];
  const float* Wv = (const float*)d_in[5];
  const float* bv = (const float*)d_in[6];
  const float* Wt = (const float*)d_in[7];
  const float* bt = (const float*)d_in[8];
  const float* Wo = (const float*)d_in[9];
  const float* bo = (const float*)d_in[10];
  const float* es = (const float*)d_in[11];

  char* ws = (char*)d_ws;
  u16* WT   = (u16*)(ws);               // 5x [1024,1024] bf16 (WqT,WkT,WvT,WtT,WoT)
  u16* XB   = (u16*)(ws + 10485760);    // [8192,1024] bf16; later AV
  u16* Qcat = (u16*)(ws + 27262976);    // [8192,2048] bf16: Q/32 | es*r_q ; later ATT
  u16* Kcat = Qcat + 16777216;          // [8192,2048] bf16: K | r_k
  u16* Vb   = (u16*)(ws + 94371840);    // [8192,1024] bf16
  u16* VT   = (u16*)(ws + 111149056);   // [4][1024,2048] bf16
  u16* WtT  = WT + 3 * 1048576;
  u16* WoT  = WT + 4 * 1048576;
  u16* ATT  = Qcat;
  u16* AV   = XB;

  float* outO = (float*)d_out;          // [4,2048,1024]
  float* outA = outO + 8388608;         // [4,2048,2048]

  cvt_x<<<8192, 256, 0, stream>>>(x, XB);
  cvt_w<<<dim3(32, 32, 5), dim3(32, 8), 0, stream>>>(Wq, Wk, Wv, Wt, Wo, WT);
  // QKV projection (128x256 tiles, grid 768)
  g8q<0, 2><<<dim3(12, 64, 1), 512, 0, stream>>>(
      XB, 1024, 0, WT, 1024, 0, Qcat, Kcat, Vb, 0, 0, 1024, bq, bk, bv, 1.f, nullptr);
  // theta (z=0: Q/32 -> es*r_q, ps=32; z=1: K -> r_k, ps=1), grid 512
  g8q<1, 2><<<dim3(4, 64, 2), 512, 0, stream>>>(
      Qcat, 2048, 16777216LL, WtT, 1024, 0, Qcat + 1024, nullptr, nullptr,
      2048, 16777216LL, 1024, bt, nullptr, nullptr, 32.f, es);
  transpose_v<<<dim3(32, 64, 4), dim3(32, 8), 0, stream>>>(Vb, VT);
  // logits = Qcat @ Kcat^T (K=2048), 256x256 tiles, grid 256
  g8q<4, 4><<<dim3(8, 8, 4), 512, 0, stream>>>(
      Qcat, 2048, 4194304LL, Kcat, 2048, 4194304LL, outA, nullptr, nullptr,
      2048, 4194304LL, 2048, nullptr, nullptr, nullptr, 1.f, nullptr);
  softmax_rows<<<8192, 256, 0, stream>>>(outA, ATT);
  // attn @ V (128x256 tiles, grid 256)
  g8q<2, 2><<<dim3(4, 16, 4), 512, 0, stream>>>(
      ATT, 2048, 4194304LL, VT, 2048, 2097152LL, AV, nullptr, nullptr,
      1024, 2097152LL, 2048, nullptr, nullptr, nullptr, 1.f, nullptr);
  // output projection (grid 256)
  g8q<3, 2><<<dim3(4, 64, 1), 512, 0, stream>>>(
      AV, 1024, 0, WoT, 1024, 0, outO, nullptr, nullptr,
      1024, 0, 1024, bo, nullptr, nullptr, 1.f, nullptr);
}

// Round 6
// 337.020 us; speedup vs baseline: 1.1042x; 1.0180x over previous
//
#include <hip/hip_runtime.h>
#include <cstdint>

typedef unsigned short u16;
typedef __attribute__((ext_vector_type(8))) short bf16x8;
typedef __attribute__((ext_vector_type(4))) float f32x4;

__device__ __forceinline__ u16 f2b(float x) {
  unsigned u = __float_as_uint(x);
  u += 0x7FFFu + ((u >> 16) & 1u);
  return (u16)(u >> 16);
}

__device__ __forceinline__ void gload16(const void* g, void* l) {
  __builtin_amdgcn_global_load_lds(
      (const __attribute__((address_space(1))) void*)g,
      (__attribute__((address_space(3))) void*)l, 16, 0, 0);
}

template <int N>
__device__ __forceinline__ void vmwait() {
  if constexpr (N == 0) asm volatile("s_waitcnt vmcnt(0)" ::: "memory");
  else if constexpr (N == 3) asm volatile("s_waitcnt vmcnt(3)" ::: "memory");
  else if constexpr (N == 4) asm volatile("s_waitcnt vmcnt(4)" ::: "memory");
  else if constexpr (N == 6) asm volatile("s_waitcnt vmcnt(6)" ::: "memory");
  else if constexpr (N == 8) asm volatile("s_waitcnt vmcnt(8)" ::: "memory");
}

// Rows are 64 bf16 = 128 B = 8 chunks of 16 B. XOR chunk with row&7 kills the
// 16-way bank conflict on column reads. Both-sides rule (m231): LDS dest
// linear, global source inverse-swizzled, read swizzled.
template <int L>
__device__ __forceinline__ void stage_half(const u16* __restrict__ G,
                                           long long ld, int kb,
                                           u16* Ldst, int tid) {
#pragma unroll
  for (int j = 0; j < L; ++j) {
    const int P = j * 512 + tid;
    const int r = P >> 3, c = P & 7;
    gload16(G + (long long)r * ld + kb + ((c ^ (r & 7)) << 3), Ldst + P * 8);
  }
}

__device__ __forceinline__ bf16x8 fr8(const u16* R, int row, int chunk) {
  return *(const bf16x8*)(R + row * 64 + ((chunk ^ (row & 7)) << 3));
}

// ---------------------------------------------------------------------------
// g3b: BM=256 x BN=128, BK=64, 512 thr (8 waves 2Mx4N), 3 LDS buffers,
// 2 phases/tile (M-halves), 16 MFMA per phase, one counted vmcnt per tile.
// Stage A(t+2) at p0, B(t+2) at p1 -> stage->wait distance 2-3 phases.
// EPI: 0=QKV split  2=bf16 out  3=f32+bias
// ---------------------------------------------------------------------------
template <int EPI>
__global__ __launch_bounds__(512, 2) void g3b(
    const u16* __restrict__ A, long long lda, long long sAz,
    const u16* __restrict__ B, long long ldb, long long sBz,
    void* __restrict__ C0, void* __restrict__ C1, void* __restrict__ C2,
    long long ldc, long long sCz, int K,
    const float* __restrict__ b0, const float* __restrict__ b1,
    const float* __restrict__ b2) {
  constexpr int AH = 8192;    // u16 per A half (128 rows x 64)
  constexpr int BSZ = 8192;   // u16 per B tile (128 rows x 64)
  constexpr int BUFU = 2 * AH + BSZ;  // 24576 u16 = 48 KB
  __shared__ __align__(16) u16 lds[3 * BUFU];  // 144 KB

  // XCD-aware bijective swizzle within the z-slice (S % 8 == 0 everywhere)
  const int gx = gridDim.x, S = gx * gridDim.y;
  const int hw = blockIdx.y * gx + blockIdx.x;
  const int l = (hw & 7) * (S >> 3) + (hw >> 3);
  const int bx = l % gx, by = l / gx;
  const int z = blockIdx.z;
  const long long tM = (long long)by * 256;
  const long long tN = (long long)bx * 128;
  const u16* GA = A + z * sAz + tM * lda;
  const u16* GB = B + z * sBz + tN * ldb;
  const int tid = threadIdx.x;
  const int NT = K >> 6;  // >= 2

  // prologue: A(0), B(0), A(1), B(1); wait tile0; barrier
  stage_half<4>(GA, lda, 0, lds, tid);
  stage_half<2>(GB, ldb, 0, lds + 2 * AH, tid);
  stage_half<4>(GA, lda, 64, lds + BUFU, tid);
  stage_half<2>(GB, ldb, 64, lds + BUFU + 2 * AH, tid);
  vmwait<6>();
  __builtin_amdgcn_s_barrier();

  const int wid = tid >> 6, lane = tid & 63;
  const int wm = wid >> 2, wn = wid & 3;
  const int lr = lane & 15, cA = lane >> 4;
  const int ar = wm * 64 + lr;
  const int br = wn * 32 + lr;
  f32x4 acc[2][4][2] = {};

  for (int t = 0; t < NT; ++t) {
    u16* cur = lds + (t % 3) * BUFU;
    u16* nx2 = lds + ((t + 2) % 3) * BUFU;
    bf16x8 a[4][2], b[2][2];

    // ---- p0: read aL + b; stage A(t+2); 16 MFMA (mh=0)
#pragma unroll
    for (int f = 0; f < 4; ++f) {
      a[f][0] = fr8(cur, ar + f * 16, cA);
      a[f][1] = fr8(cur, ar + f * 16, 4 + cA);
    }
#pragma unroll
    for (int g = 0; g < 2; ++g) {
      b[g][0] = fr8(cur + 2 * AH, br + g * 16, cA);
      b[g][1] = fr8(cur + 2 * AH, br + g * 16, 4 + cA);
    }
    if (t + 2 < NT) stage_half<4>(GA, lda, (t + 2) * 64, nx2, tid);
    asm volatile("s_waitcnt lgkmcnt(8)" ::: "memory");
    __builtin_amdgcn_s_barrier();
    asm volatile("s_waitcnt lgkmcnt(0)" ::: "memory");
    __builtin_amdgcn_s_setprio(1);
#pragma unroll
    for (int kh = 0; kh < 2; ++kh)
#pragma unroll
      for (int f = 0; f < 4; ++f)
#pragma unroll
        for (int g = 0; g < 2; ++g)
          acc[0][f][g] = __builtin_amdgcn_mfma_f32_16x16x32_bf16(
              a[f][kh], b[g][kh], acc[0][f][g], 0, 0, 0);
    __builtin_amdgcn_s_setprio(0);
    __builtin_amdgcn_s_barrier();

    // ---- p1: read aH (reuse b); stage B(t+2); vmcnt for tile t+1; 16 MFMA
#pragma unroll
    for (int f = 0; f < 4; ++f) {
      a[f][0] = fr8(cur + AH, ar + f * 16, cA);
      a[f][1] = fr8(cur + AH, ar + f * 16, 4 + cA);
    }
    if (t + 2 < NT) stage_half<2>(GB, ldb, (t + 2) * 64, nx2 + 2 * AH, tid);
    if (t < NT - 2) vmwait<6>(); else vmwait<0>();
    __builtin_amdgcn_s_barrier();
    asm volatile("s_waitcnt lgkmcnt(0)" ::: "memory");
    __builtin_amdgcn_s_setprio(1);
#pragma unroll
    for (int kh = 0; kh < 2; ++kh)
#pragma unroll
      for (int f = 0; f < 4; ++f)
#pragma unroll
        for (int g = 0; g < 2; ++g)
          acc[1][f][g] = __builtin_amdgcn_mfma_f32_16x16x32_bf16(
              a[f][kh], b[g][kh], acc[1][f][g], 0, 0, 0);
    __builtin_amdgcn_s_setprio(0);
    __builtin_amdgcn_s_barrier();
  }

  // epilogue: C/D map col=lane&15, row=(lane>>4)*4+reg
  const int rr = (lane >> 4) << 2;
#pragma unroll
  for (int mh = 0; mh < 2; ++mh) {
#pragma unroll
    for (int f = 0; f < 4; ++f) {
#pragma unroll
      for (int g = 0; g < 2; ++g) {
        const int col = (int)tN + wn * 32 + g * 16 + lr;
        const f32x4 vv = acc[mh][f][g];
#pragma unroll
        for (int r = 0; r < 4; ++r) {
          const long long row = tM + mh * 128 + wm * 64 + f * 16 + rr + r;
          const float v = vv[r];
          if constexpr (EPI == 0) {
            const int gg = col >> 10, cc = col & 1023;
            if (gg == 0)      ((u16*)C0)[row * 2048 + cc] = f2b((v + b0[cc]) * 0.03125f);
            else if (gg == 1) ((u16*)C1)[row * 2048 + cc] = f2b(v + b1[cc]);
            else              ((u16*)C2)[row * 1024 + cc] = f2b(v + b2[cc]);
          } else if constexpr (EPI == 2) {
            ((u16*)C0)[z * sCz + row * ldc + col] = f2b(v);
          } else {
            ((float*)C0)[z * sCz + row * ldc + col] = v + b0[col];
          }
        }
      }
    }
  }
}

// ---------------------------------------------------------------------------
// g8q: proven 4-phase quadrant kernel (round 5), FM=4 only: 256x256 tiles.
// EPI: 1=theta->cat halves  4=f32 plain
// ---------------------------------------------------------------------------
template <int FM, int MODE>  // MODE: 0 steady, 1 t=NT-2, 2 t=NT-1
__device__ __forceinline__ void tile_body(
    u16* cur, u16* oth, const u16* GA_lo, const u16* GA_hi,
    const u16* GB_lo, const u16* GB_hi, long long lda, long long ldb,
    int kb1, int kb2, int wm, int wn, int lr, int cA, int tid,
    f32x4 (&acc)[2][2][FM][2]) {
  constexpr int LA = FM / 2, LB = 2;
  constexpr int AH = 2048 * FM, BH = 8192;
  const u16* Alo = cur;
  const u16* Ahi = cur + AH;
  const u16* Blo = cur + 2 * AH;
  const u16* Bhi = cur + 2 * AH + BH;
  const int ar = wm * (FM * 16) + lr;
  const int br = wn * 32 + lr;
  bf16x8 a[FM][2], b[2][2];

  // ---- p0: read aL + bL; stage Ahi(t+1)->oth; vmcnt ensures Ahi(t),Bhi(t)
#pragma unroll
  for (int f = 0; f < FM; ++f) {
    a[f][0] = fr8(Alo, ar + f * 16, cA);
    a[f][1] = fr8(Alo, ar + f * 16, 4 + cA);
  }
#pragma unroll
  for (int g = 0; g < 2; ++g) {
    b[g][0] = fr8(Blo, br + g * 16, cA);
    b[g][1] = fr8(Blo, br + g * 16, 4 + cA);
  }
  if constexpr (MODE < 2) stage_half<LA>(GA_hi, lda, kb1, oth + AH, tid);
  if constexpr (FM == 4) asm volatile("s_waitcnt lgkmcnt(8)" ::: "memory");
  if constexpr (MODE < 2) vmwait<2 * LA + 2>(); else vmwait<0>();
  __builtin_amdgcn_s_barrier();
  asm volatile("s_waitcnt lgkmcnt(0)" ::: "memory");
  __builtin_amdgcn_s_setprio(1);
#pragma unroll
  for (int kh = 0; kh < 2; ++kh)
#pragma unroll
    for (int f = 0; f < FM; ++f)
#pragma unroll
      for (int g = 0; g < 2; ++g)
        acc[0][0][f][g] = __builtin_amdgcn_mfma_f32_16x16x32_bf16(
            a[f][kh], b[g][kh], acc[0][0][f][g], 0, 0, 0);
  __builtin_amdgcn_s_setprio(0);
  __builtin_amdgcn_s_barrier();

  // ---- p1: read bH (reuse a); stage Bhi(t+1)->oth
#pragma unroll
  for (int g = 0; g < 2; ++g) {
    b[g][0] = fr8(Bhi, br + g * 16, cA);
    b[g][1] = fr8(Bhi, br + g * 16, 4 + cA);
  }
  if constexpr (MODE < 2) stage_half<LB>(GB_hi, ldb, kb1, oth + 2 * AH + BH, tid);
  __builtin_amdgcn_s_barrier();
  asm volatile("s_waitcnt lgkmcnt(0)" ::: "memory");
  __builtin_amdgcn_s_setprio(1);
#pragma unroll
  for (int kh = 0; kh < 2; ++kh)
#pragma unroll
    for (int f = 0; f < FM; ++f)
#pragma unroll
      for (int g = 0; g < 2; ++g)
        acc[0][1][f][g] = __builtin_amdgcn_mfma_f32_16x16x32_bf16(
            a[f][kh], b[g][kh], acc[0][1][f][g], 0, 0, 0);
  __builtin_amdgcn_s_setprio(0);
  __builtin_amdgcn_s_barrier();

  // ---- p2: read aH + bL; stage Alo(t+2)->cur
#pragma unroll
  for (int f = 0; f < FM; ++f) {
    a[f][0] = fr8(Ahi, ar + f * 16, cA);
    a[f][1] = fr8(Ahi, ar + f * 16, 4 + cA);
  }
#pragma unroll
  for (int g = 0; g < 2; ++g) {
    b[g][0] = fr8(Blo, br + g * 16, cA);
    b[g][1] = fr8(Blo, br + g * 16, 4 + cA);
  }
  if constexpr (MODE == 0) stage_half<LA>(GA_lo, lda, kb2, cur, tid);
  if constexpr (FM == 4) asm volatile("s_waitcnt lgkmcnt(8)" ::: "memory");
  __builtin_amdgcn_s_barrier();
  asm volatile("s_waitcnt lgkmcnt(0)" ::: "memory");
  __builtin_amdgcn_s_setprio(1);
#pragma unroll
  for (int kh = 0; kh < 2; ++kh)
#pragma unroll
    for (int f = 0; f < FM; ++f)
#pragma unroll
      for (int g = 0; g < 2; ++g)
        acc[1][0][f][g] = __builtin_amdgcn_mfma_f32_16x16x32_bf16(
            a[f][kh], b[g][kh], acc[1][0][f][g], 0, 0, 0);
  __builtin_amdgcn_s_setprio(0);
  __builtin_amdgcn_s_barrier();

  // ---- p3: read bH; stage Blo(t+2)->cur; vmcnt ensures Alo(t+1),Blo(t+1)
#pragma unroll
  for (int g = 0; g < 2; ++g) {
    b[g][0] = fr8(Bhi, br + g * 16, cA);
    b[g][1] = fr8(Bhi, br + g * 16, 4 + cA);
  }
  if constexpr (MODE == 0) stage_half<LB>(GB_lo, ldb, kb2, cur + 2 * AH, tid);
  if constexpr (MODE == 0) vmwait<2 * LA + 4>();
  else if constexpr (MODE == 1) vmwait<LA + 2>();
  __builtin_amdgcn_s_barrier();
  asm volatile("s_waitcnt lgkmcnt(0)" ::: "memory");
  __builtin_amdgcn_s_setprio(1);
#pragma unroll
  for (int kh = 0; kh < 2; ++kh)
#pragma unroll
    for (int f = 0; f < FM; ++f)
#pragma unroll
      for (int g = 0; g < 2; ++g)
        acc[1][1][f][g] = __builtin_amdgcn_mfma_f32_16x16x32_bf16(
            a[f][kh], b[g][kh], acc[1][1][f][g], 0, 0, 0);
  __builtin_amdgcn_s_setprio(0);
  __builtin_amdgcn_s_barrier();
}

template <int EPI, int FM>
__global__ __launch_bounds__(512, 2) void g8q(
    const u16* __restrict__ A, long long lda, long long sAz,
    const u16* __restrict__ B, long long ldb, long long sBz,
    void* __restrict__ C0, void* __restrict__ C1, void* __restrict__ C2,
    long long ldc, long long sCz, int K,
    const float* __restrict__ b0, const float* __restrict__ b1,
    const float* __restrict__ b2, float preScale, const float* __restrict__ esp) {
  constexpr int BM = 64 * FM;
  constexpr int LA = FM / 2, LB = 2;
  constexpr int AH = 2048 * FM, BH = 8192;
  constexpr int BUFU = 2 * AH + 2 * BH;
  __shared__ __align__(16) u16 lds[2 * BUFU];
  u16* buf0 = lds;
  u16* buf1 = lds + BUFU;

  const int gx = gridDim.x, S = gx * gridDim.y;
  const int hw = blockIdx.y * gx + blockIdx.x;
  const int l = (hw & 7) * (S >> 3) + (hw >> 3);
  const int bx = l % gx, by = l / gx;
  const int z = blockIdx.z;
  const long long tM = (long long)by * BM;
  const long long tN = (long long)bx * 256;
  const u16* Ab = A + z * sAz + tM * lda;
  const u16* Bb = B + z * sBz + tN * ldb;
  const u16* GA_lo = Ab;
  const u16* GA_hi = Ab + (long long)(BM / 2) * lda;
  const u16* GB_lo = Bb;
  const u16* GB_hi = Bb + 128 * ldb;
  const int tid = threadIdx.x;
  const int NT = K >> 6;  // NT even, >= 4

  stage_half<LA>(GA_lo, lda, 0, buf0, tid);
  stage_half<LB>(GB_lo, ldb, 0, buf0 + 2 * AH, tid);
  stage_half<LA>(GA_hi, lda, 0, buf0 + AH, tid);
  stage_half<LB>(GB_hi, ldb, 0, buf0 + 2 * AH + BH, tid);
  stage_half<LA>(GA_lo, lda, 64, buf1, tid);
  stage_half<LB>(GB_lo, ldb, 64, buf1 + 2 * AH, tid);
  vmwait<2 * LA + 4>();
  __builtin_amdgcn_s_barrier();

  const int wid = tid >> 6, lane = tid & 63;
  const int wm = wid >> 2, wn = wid & 3;
  const int lr = lane & 15, cA = lane >> 4;
  f32x4 acc[2][2][FM][2] = {};

  for (int t = 0; t + 2 < NT; t += 2) {
    tile_body<FM, 0>(buf0, buf1, GA_lo, GA_hi, GB_lo, GB_hi, lda, ldb,
                     (t + 1) * 64, (t + 2) * 64, wm, wn, lr, cA, tid, acc);
    tile_body<FM, 0>(buf1, buf0, GA_lo, GA_hi, GB_lo, GB_hi, lda, ldb,
                     (t + 2) * 64, (t + 3) * 64, wm, wn, lr, cA, tid, acc);
  }
  tile_body<FM, 1>(buf0, buf1, GA_lo, GA_hi, GB_lo, GB_hi, lda, ldb,
                   (NT - 1) * 64, 0, wm, wn, lr, cA, tid, acc);
  tile_body<FM, 2>(buf1, buf0, GA_lo, GA_hi, GB_lo, GB_hi, lda, ldb,
                   0, 0, wm, wn, lr, cA, tid, acc);

  const int rr = (lane >> 4) << 2;
  float ps = preScale, mul = 1.0f;
  if constexpr (EPI == 1) {
    ps = (z == 0) ? preScale : 1.0f;
    mul = (z == 0) ? esp[0] : 1.0f;
  }
#pragma unroll
  for (int mh = 0; mh < 2; ++mh) {
#pragma unroll
    for (int nh = 0; nh < 2; ++nh) {
#pragma unroll
      for (int f = 0; f < FM; ++f) {
#pragma unroll
        for (int g = 0; g < 2; ++g) {
          const int col = (int)tN + nh * 128 + wn * 32 + g * 16 + lr;
          const f32x4 vv = acc[mh][nh][f][g];
#pragma unroll
          for (int r = 0; r < 4; ++r) {
            const long long row =
                tM + mh * (BM / 2) + wm * (FM * 16) + f * 16 + rr + r;
            const float v = vv[r];
            if constexpr (EPI == 1) {
              const float tt = v * ps + b0[col];
              const float sg = 1.f / (1.f + __expf(-tt));
              ((u16*)C0)[z * sCz + row * ldc + col] = f2b(mul * cospif(sg));
            } else {
              ((float*)C0)[z * sCz + row * ldc + col] = v;
            }
          }
        }
      }
    }
  }
}

// row softmax over [8192][2048]: fp32 in-place + bf16 copy
__global__ __launch_bounds__(256) void softmax_rows(float* __restrict__ L,
                                                    u16* __restrict__ AB) {
  const long long row = blockIdx.x;
  float4* p4 = (float4*)(L + row * 2048);
  const int tid = threadIdx.x;
  float4 a = p4[tid], b = p4[tid + 256];
  float m = fmaxf(fmaxf(fmaxf(a.x, a.y), fmaxf(a.z, a.w)),
                  fmaxf(fmaxf(b.x, b.y), fmaxf(b.z, b.w)));
#pragma unroll
  for (int o = 32; o > 0; o >>= 1) m = fmaxf(m, __shfl_xor(m, o));
  __shared__ float rmax[4], rsum[4];
  const int wid = tid >> 6, lane = tid & 63;
  if (lane == 0) rmax[wid] = m;
  __syncthreads();
  m = fmaxf(fmaxf(rmax[0], rmax[1]), fmaxf(rmax[2], rmax[3]));
  a.x = __expf(a.x - m); a.y = __expf(a.y - m);
  a.z = __expf(a.z - m); a.w = __expf(a.w - m);
  b.x = __expf(b.x - m); b.y = __expf(b.y - m);
  b.z = __expf(b.z - m); b.w = __expf(b.w - m);
  float s = a.x + a.y + a.z + a.w + b.x + b.y + b.z + b.w;
#pragma unroll
  for (int o = 32; o > 0; o >>= 1) s += __shfl_xor(s, o);
  if (lane == 0) rsum[wid] = s;
  __syncthreads();
  s = rsum[0] + rsum[1] + rsum[2] + rsum[3];
  const float inv = 1.0f / s;
  a.x *= inv; a.y *= inv; a.z *= inv; a.w *= inv;
  b.x *= inv; b.y *= inv; b.z *= inv; b.w *= inv;
  p4[tid] = a;
  p4[tid + 256] = b;
  ushort4* o4 = (ushort4*)(AB + row * 2048);
  o4[tid]       = make_ushort4(f2b(a.x), f2b(a.y), f2b(a.z), f2b(a.w));
  o4[tid + 256] = make_ushort4(f2b(b.x), f2b(b.y), f2b(b.z), f2b(b.w));
}

__global__ __launch_bounds__(256) void cvt_x(const float* __restrict__ X,
                                             u16* __restrict__ XB) {
  const int i = blockIdx.x * 256 + threadIdx.x;
  float4 v = ((const float4*)X)[i];
  ((ushort4*)XB)[i] = make_ushort4(f2b(v.x), f2b(v.y), f2b(v.z), f2b(v.w));
}

// transpose+convert 5 weight matrices [1024,1024] f32 -> bf16 W^T
__global__ void cvt_w(const float* __restrict__ W0, const float* __restrict__ W1,
                      const float* __restrict__ W2, const float* __restrict__ W3,
                      const float* __restrict__ W4, u16* __restrict__ WT) {
  __shared__ float t[32][33];
  const int z = blockIdx.z;
  const float* W = (z == 0) ? W0 : (z == 1) ? W1 : (z == 2) ? W2 : (z == 3) ? W3 : W4;
  u16* D = WT + (long long)z * 1024 * 1024;
  const int c0 = blockIdx.x * 32, r0 = blockIdx.y * 32;
  const int tx = threadIdx.x, ty = threadIdx.y;
#pragma unroll
  for (int i = 0; i < 4; ++i)
    t[ty + i * 8][tx] = W[(long long)(r0 + ty + i * 8) * 1024 + c0 + tx];
  __syncthreads();
#pragma unroll
  for (int i = 0; i < 4; ++i)
    D[(long long)(c0 + ty + i * 8) * 1024 + r0 + tx] = f2b(t[tx][ty + i * 8]);
}

// Vb [8192,1024] bf16 -> VT [4][1024,2048] bf16
__global__ void transpose_v(const u16* __restrict__ Vb, u16* __restrict__ VT) {
  __shared__ u16 t[32][33];
  const int b = blockIdx.z;
  const u16* V = Vb + (long long)b * 2048 * 1024;
  u16* O = VT + (long long)b * 1024 * 2048;
  const int d0 = blockIdx.x * 32, s0 = blockIdx.y * 32;
  const int tx = threadIdx.x, ty = threadIdx.y;
#pragma unroll
  for (int i = 0; i < 4; ++i)
    t[ty + i * 8][tx] = V[(long long)(s0 + ty + i * 8) * 1024 + d0 + tx];
  __syncthreads();
#pragma unroll
  for (int i = 0; i < 4; ++i)
    O[(long long)(d0 + ty + i * 8) * 2048 + s0 + tx] = t[tx][ty + i * 8];
}

extern "C" void kernel_launch(void* const* d_in, const int* in_sizes, int n_in,
                              void* d_out, int out_size, void* d_ws,
                              size_t ws_size, hipStream_t stream) {
  const float* x  = (const float*)d_in[0];
  const float* Wq = (const float*)d_in[1];
  const float* bq = (const float*)d_in[2];
  const float* Wk = (const float*)d_in[3];
  const float* bk = (const float*)d_in[4];
  const float* Wv = (const float*)d_in[5];
  const float* bv = (const float*)d_in[6];
  const float* Wt = (const float*)d_in[7];
  const float* bt = (const float*)d_in[8];
  const float* Wo = (const float*)d_in[9];
  const float* bo = (const float*)d_in[10];
  const float* es = (const float*)d_in[11];

  char* ws = (char*)d_ws;
  u16* WT   = (u16*)(ws);               // 5x [1024,1024] bf16 (WqT,WkT,WvT,WtT,WoT)
  u16* XB   = (u16*)(ws + 10485760);    // [8192,1024] bf16; later AV
  u16* Qcat = (u16*)(ws + 27262976);    // [8192,2048] bf16: Q/32 | es*r_q ; later ATT
  u16* Kcat = Qcat + 16777216;          // [8192,2048] bf16: K | r_k
  u16* Vb   = (u16*)(ws + 94371840);    // [8192,1024] bf16
  u16* VT   = (u16*)(ws + 111149056);   // [4][1024,2048] bf16
  u16* WtT  = WT + 3 * 1048576;
  u16* WoT  = WT + 4 * 1048576;
  u16* ATT  = Qcat;
  u16* AV   = XB;

  float* outO = (float*)d_out;          // [4,2048,1024]
  float* outA = outO + 8388608;         // [4,2048,2048]

  cvt_x<<<8192, 256, 0, stream>>>(x, XB);
  cvt_w<<<dim3(32, 32, 5), dim3(32, 8), 0, stream>>>(Wq, Wk, Wv, Wt, Wo, WT);
  // QKV projection (256x128 tiles, grid 768 = 3 clean rounds)
  g3b<0><<<dim3(24, 32, 1), 512, 0, stream>>>(
      XB, 1024, 0, WT, 1024, 0, Qcat, Kcat, Vb, 0, 0, 1024, bq, bk, bv);
  // theta (z=0: Q/32 -> es*r_q, ps=32; z=1: K -> r_k, ps=1), grid 256
  g8q<1, 4><<<dim3(4, 32, 2), 512, 0, stream>>>(
      Qcat, 2048, 16777216LL, WtT, 1024, 0, Qcat + 1024, nullptr, nullptr,
      2048, 16777216LL, 1024, bt, nullptr, nullptr, 32.f, es);
  transpose_v<<<dim3(32, 64, 4), dim3(32, 8), 0, stream>>>(Vb, VT);
  // logits = Qcat @ Kcat^T (K=2048), 256x256 tiles, grid 256
  g8q<4, 4><<<dim3(8, 8, 4), 512, 0, stream>>>(
      Qcat, 2048, 4194304LL, Kcat, 2048, 4194304LL, outA, nullptr, nullptr,
      2048, 4194304LL, 2048, nullptr, nullptr, nullptr, 1.f, nullptr);
  softmax_rows<<<8192, 256, 0, stream>>>(outA, ATT);
  // attn @ V (256x128 tiles, grid 256)
  g3b<2><<<dim3(8, 8, 4), 512, 0, stream>>>(
      ATT, 2048, 4194304LL, VT, 2048, 2097152LL, AV, nullptr, nullptr,
      1024, 2097152LL, 2048, nullptr, nullptr, nullptr);
  // output projection (grid 256)
  g3b<3><<<dim3(8, 32, 1), 512, 0, stream>>>(
      AV, 1024, 0, WoT, 1024, 0, outO, nullptr, nullptr,
      1024, 0, 1024, bo, nullptr, nullptr);
}